// Round 4
// baseline (127.193 us; speedup 1.0000x reference)
//
#include <hip/hip_runtime.h>

// x: [B=2, C=16, D1=8, D2=8, D3=64, D4=64] fp32
// w: [O=32, I=16, 3,3,3,3] fp32
// out = relu(conv4d_valid(x, w)): [2, 32, 6, 6, 62, 62] fp32
//
// Per tap (k1,k2,k3,k4): D[32 e4-pix][32 o] += A[pix][16 c] * B[16 c][32 o]
// via v_mfma_f32_32x32x16_bf16 (fp32 acc). Barrier-free: A-frags read
// directly from the bf16 channel-last tensor xb through L1 (every staged
// byte would be read 9x anyway; L1 serves the reuse without any
// __syncthreads/vmcnt(0) drain). One wave per block = fluid scheduling.

typedef __attribute__((ext_vector_type(8))) __bf16 bf16x8;
typedef __attribute__((ext_vector_type(16))) float f32x16;

#define CSTRIDE 262144  // x channel stride, elements

#define WT_OFF 0       // wT[t81][o32][c16] bf16 = 83 KB
#define XB_OFF 131072  // xb[b][d1][d2][d3][ch2][col64][c8] bf16 = 16.78 MB

// ---- prep: blocks 0..511 transform x -> xb; blocks 512..543 build wT
__global__ __launch_bounds__(256) void prep(const float* __restrict__ x,
                                            const float* __restrict__ w,
                                            unsigned char* __restrict__ ws) {
  int blk = blockIdx.x;
  if (blk < 512) {
    __bf16* xb = (__bf16*)(ws + XB_OFF);
    int n = blk * 256 + threadIdx.x;  // (b,d1,d2,d3,colgroup4)
    int cg = n & 15;
    int d3 = (n >> 4) & 63;
    int d2 = (n >> 10) & 7;
    int d1 = (n >> 13) & 7;
    int b = n >> 16;
    const float* gx =
        x + ((((b * 16) * 8 + d1) * 8 + d2) * 64 + d3) * 64 + cg * 4;
    float4 v[16];
#pragma unroll
    for (int c = 0; c < 16; ++c)
      v[c] = *(const float4*)(gx + (size_t)c * CSTRIDE);
    __bf16* row = xb + ((((b * 8 + d1) * 8 + d2) * 64 + d3) * 1024);
#pragma unroll
    for (int ch = 0; ch < 2; ++ch) {
#pragma unroll
      for (int j = 0; j < 4; ++j) {
        bf16x8 o;
#pragma unroll
        for (int cc = 0; cc < 8; ++cc)
          o[cc] = (__bf16)(((const float*)&v[ch * 8 + cc])[j]);
        *(bf16x8*)(row + ch * 512 + (cg * 4 + j) * 8) = o;
      }
    }
  } else {
    int o = blk - 512;  // one output channel per block
    __bf16* wT = (__bf16*)(ws + WT_OFF);
#pragma unroll
    for (int base = 0; base < 1296; base += 256) {
      int idx = base + threadIdx.x;
      if (idx < 1296) {
        int c = idx / 81, t = idx % 81;
        wT[t * 512 + o * 16 + c] = (__bf16)w[o * 1296 + idx];
      }
    }
  }
}

// one wave per block; task = (b, e1, e2, e4-half, 4 consecutive e3 rows)
__global__ __launch_bounds__(64, 3) void conv_mfma(
    const unsigned char* __restrict__ ws, float* __restrict__ out) {
  const unsigned char* wTb = ws + WT_OFF;
  const unsigned char* xbb = ws + XB_OFF;

  int bid = blockIdx.x;
  int c3 = bid & 15;         // e3 chunk of 4 (rows 60..63 partially masked)
  int th = (bid >> 4) & 1;   // e4 half
  int t = bid >> 5;
  int e2 = t % 6;
  t /= 6;
  int e1 = t % 6;
  int b = t / 6;
  int r0 = c3 * 4;

  int lane = threadIdx.x;
  int m32 = lane & 31;
  int half = lane >> 5;

  // per-lane constant byte offsets (A: pixel col + channel half; B: o + c-half)
  int aoff = half * 1024 + (th * 32 + m32) * 16;
  int woff = m32 * 32 + half * 16;

  f32x16 acc[4];
#pragma unroll
  for (int i = 0; i < 4; ++i)
#pragma unroll
    for (int r = 0; r < 16; ++r) acc[i][r] = 0.f;

  for (int k1 = 0; k1 < 3; ++k1) {
    for (int k2 = 0; k2 < 3; ++k2) {
      const unsigned char* abase =
          xbb +
          (size_t)(((b * 8 + e1 + k1) * 8 + e2 + k2) * 64 + r0) * 2048 + aoff;
      const unsigned char* wbase = wTb + (k1 * 3 + k2) * 9216 + woff;
#pragma unroll
      for (int k4 = 0; k4 < 3; ++k4) {
        // 6 distinct d3-row fragments serve all (k3,i) with i+k3=j
        bf16x8 arow[6];
#pragma unroll
        for (int j = 0; j < 6; ++j)
          arow[j] = *(const bf16x8*)(abase + j * 2048 + k4 * 16);
#pragma unroll
        for (int k3 = 0; k3 < 3; ++k3) {
          bf16x8 bf = *(const bf16x8*)(wbase + (k3 * 3 + k4) * 1024);
#pragma unroll
          for (int i = 0; i < 4; ++i)
            acc[i] = __builtin_amdgcn_mfma_f32_32x32x16_bf16(arow[i + k3], bf,
                                                             acc[i], 0, 0, 0);
        }
      }
    }
  }

  // epilogue: LDS transpose (stride 33, conflict-free), ReLU, coalesced store
  __shared__ float sc[32 * 33];
  int e4 = th * 32 + m32;
  size_t obase_be = ((size_t)b * 32 * 36 + e1 * 6 + e2) * 3844;
#pragma unroll
  for (int i = 0; i < 4; ++i) {
    int e3 = r0 + i;
    if (e3 >= 62) break;
    __syncthreads();
#pragma unroll
    for (int r = 0; r < 16; ++r) {
      int m = (r & 3) + 8 * (r >> 2) + 4 * half;  // pixel row in tile
      sc[m * 33 + m32] = acc[i][r];               // [pix][o]
    }
    __syncthreads();
#pragma unroll
    for (int it = 0; it < 16; ++it) {
      int o = it * 2 + half;
      float v = fmaxf(sc[m32 * 33 + o], 0.f);
      if (e4 < 62)
        out[obase_be + (size_t)o * 138384 + (size_t)e3 * 62 + e4] = v;
    }
  }
}

extern "C" void kernel_launch(void* const* d_in, const int* in_sizes, int n_in,
                              void* d_out, int out_size, void* d_ws,
                              size_t ws_size, hipStream_t stream) {
  const float* x = (const float*)d_in[0];
  const float* w = (const float*)d_in[1];
  float* out = (float*)d_out;
  unsigned char* ws = (unsigned char*)d_ws;
  prep<<<dim3(544), dim3(256), 0, stream>>>(x, w, ws);
  conv_mfma<<<dim3(2 * 6 * 6 * 2 * 16), dim3(64), 0, stream>>>(ws, out);
}

// Round 5
// 114.566 us; speedup vs baseline: 1.1102x; 1.1102x over previous
//
#include <hip/hip_runtime.h>

// x: [B=2, C=16, D1=8, D2=8, D3=64, D4=64] fp32
// w: [O=32, I=16, 3,3,3,3] fp32
// out = relu(conv4d_valid(x, w)): [2, 32, 6, 6, 62, 62] fp32
//
// Per tap: D[32 e4-pix][32 o] += A[pix][16 c] * B[16 c][32 o]
// (v_mfma_f32_32x32x16_bf16, fp32 acc, 81 taps).
// Block = (b,e1,e2, 6 e3 rows, 64 e4). A staged to LDS once per (k1,k2)
// phase (16 KB, global_load_lds w16, double-buffered) and reused by all
// 9 (k3,k4) taps from LDS. B read per-phase from L2-hot wT (83 KB).
// bid = chunk*72 + g keeps a (b,e1,e2) group on one XCD (72 % 8 == 0).

typedef __attribute__((ext_vector_type(8))) __bf16 bf16x8;
typedef __attribute__((ext_vector_type(16))) float f32x16;

#define CSTRIDE 262144  // x channel stride, elements

#define WT_OFF 0       // wT[t81][o32][c16] bf16 = 83 KB
#define XB_OFF 131072  // xb[b][d1][d2][d3][ch2][col64][c8] bf16 = 16.78 MB
#define ABUF 16640     // 16 KB staged rows + 256 B halo-overrun pad
#define SCR_OFF (2 * ABUF)  // epilogue scratch: 4 waves * 4224 B

typedef __attribute__((address_space(1))) const unsigned int gu32;
typedef __attribute__((address_space(3))) unsigned int lu32;

__device__ __forceinline__ void async_cp16(const void* g, void* l) {
  __builtin_amdgcn_global_load_lds((gu32*)g, (lu32*)l, 16, 0, 0);
}

// ---- prep: blocks 0..511 transform x -> xb; blocks 512..543 build wT
__global__ __launch_bounds__(256) void prep(const float* __restrict__ x,
                                            const float* __restrict__ w,
                                            unsigned char* __restrict__ ws) {
  int blk = blockIdx.x;
  if (blk < 512) {
    __bf16* xb = (__bf16*)(ws + XB_OFF);
    int n = blk * 256 + threadIdx.x;  // (b,d1,d2,d3,colgroup4)
    int cg = n & 15;
    int d3 = (n >> 4) & 63;
    int d2 = (n >> 10) & 7;
    int d1 = (n >> 13) & 7;
    int b = n >> 16;
    const float* gx =
        x + ((((b * 16) * 8 + d1) * 8 + d2) * 64 + d3) * 64 + cg * 4;
    float4 v[16];
#pragma unroll
    for (int c = 0; c < 16; ++c)
      v[c] = *(const float4*)(gx + (size_t)c * CSTRIDE);
    __bf16* row = xb + ((((b * 8 + d1) * 8 + d2) * 64 + d3) * 1024);
#pragma unroll
    for (int ch = 0; ch < 2; ++ch) {
#pragma unroll
      for (int j = 0; j < 4; ++j) {
        bf16x8 o;
#pragma unroll
        for (int cc = 0; cc < 8; ++cc)
          o[cc] = (__bf16)(((const float*)&v[ch * 8 + cc])[j]);
        *(bf16x8*)(row + ch * 512 + (cg * 4 + j) * 8) = o;
      }
    }
  } else {
    int o = blk - 512;
    __bf16* wT = (__bf16*)(ws + WT_OFF);
#pragma unroll
    for (int base = 0; base < 1296; base += 256) {
      int idx = base + threadIdx.x;
      if (idx < 1296) {
        int c = idx / 81, t = idx % 81;
        wT[t * 512 + o * 16 + c] = (__bf16)w[o * 1296 + idx];
      }
    }
  }
}

// NT = tiles per wave (3 normal chunks, 1 for the 2-row tail chunk)
template <int NT>
__device__ __forceinline__ void conv_body(
    const unsigned char* __restrict__ wTb, const unsigned char* __restrict__ xbb,
    float* __restrict__ out, unsigned char* lds, int b, int e1, int e2,
    int r0) {
  int lane = threadIdx.x & 63;
  int wave = threadIdx.x >> 6;
  int m32 = lane & 31;
  int half = lane >> 5;
  int rg = wave >> 1;  // row-group
  int th = wave & 1;   // e4 half
  int rowbase = rg * NT;
  const int nck = (NT * 2 + 2) * 2;  // staged 1KB chunks: (rows+2 halo)*2

  int ab_off = half * 1024 + (th * 32 + m32) * 16;

  f32x16 acc[NT];
#pragma unroll
  for (int i = 0; i < NT; ++i)
#pragma unroll
    for (int r = 0; r < 16; ++r) acc[i][r] = 0.f;

  // prologue: stage phase 0 into buf 0
  {
    const unsigned char* g =
        xbb + (size_t)(((b * 8 + e1) * 8 + e2) * 64 + r0) * 2048;
#pragma unroll
    for (int j = 0; j < 4; ++j) {
      int ck = j * 4 + wave;
      if (ck < nck) async_cp16(g + ck * 1024 + lane * 16, lds + ck * 1024);
    }
  }

  for (int p = 0; p < 9; ++p) {  // phase = (k1,k2)
    __syncthreads();  // stage(p) visible; buf[(p+1)&1] free
    // B-frags FIRST so their vmcnt wait leaves stage(p+1) in flight
    const unsigned char* wp = wTb + p * 9216 + m32 * 32 + half * 16;
    bf16x8 bfr[9];
#pragma unroll
    for (int t9 = 0; t9 < 9; ++t9)
      bfr[t9] = *(const bf16x8*)(wp + t9 * 1024);
    if (p < 8) {
      int np = p + 1;
      int nk1 = np / 3, nk2 = np - nk1 * 3;
      const unsigned char* g =
          xbb + (size_t)(((b * 8 + e1 + nk1) * 8 + e2 + nk2) * 64 + r0) * 2048;
      unsigned char* dst = lds + (np & 1) * ABUF;
#pragma unroll
      for (int j = 0; j < 4; ++j) {
        int ck = j * 4 + wave;
        if (ck < nck) async_cp16(g + ck * 1024 + lane * 16, dst + ck * 1024);
      }
    }
    // compute: A from LDS; 5 row-frags serve 9 MFMAs per k4 (k3 overlap)
    const unsigned char* abase =
        lds + (p & 1) * ABUF + rowbase * 2048 + ab_off;
#pragma unroll
    for (int k4 = 0; k4 < 3; ++k4) {
      bf16x8 arow[NT + 2];
#pragma unroll
      for (int j = 0; j < NT + 2; ++j)
        arow[j] = *(const bf16x8*)(abase + j * 2048 + k4 * 16);
#pragma unroll
      for (int k3 = 0; k3 < 3; ++k3) {
        bf16x8 bf = bfr[k3 * 3 + k4];
#pragma unroll
        for (int i = 0; i < NT; ++i)
          acc[i] = __builtin_amdgcn_mfma_f32_32x32x16_bf16(arow[i + k3], bf,
                                                           acc[i], 0, 0, 0);
      }
    }
  }
  __syncthreads();  // all ds_reads done before scratch overwrite

  // epilogue: per-wave LDS transpose (stride 33), ReLU, coalesced store
  float* sc = (float*)(void*)(lds + SCR_OFF) + wave * 1056;
  int e4 = th * 32 + m32;
#pragma unroll
  for (int i = 0; i < NT; ++i) {
    int e3 = r0 + rowbase + i;
#pragma unroll
    for (int r = 0; r < 16; ++r) {
      int m = (r & 3) + 8 * (r >> 2) + 4 * half;  // pixel row in tile
      sc[m * 33 + m32] = acc[i][r];               // [pix][o]
    }
    size_t obase =
        ((((size_t)b * 32) * 6 + e1) * 6 + e2) * 3844 + (size_t)e3 * 62;
#pragma unroll
    for (int it = 0; it < 16; ++it) {
      int o = it * 2 + half;
      float v = fmaxf(sc[m32 * 33 + o], 0.f);
      if (e4 < 62) out[obase + (size_t)o * 138384 + e4] = v;
    }
  }
}

__global__ __launch_bounds__(256, 3) void conv_mfma(
    const unsigned char* __restrict__ ws, float* __restrict__ out) {
  const unsigned char* wTb = ws + WT_OFF;
  const unsigned char* xbb = ws + XB_OFF;

  __shared__ __align__(16) unsigned char lds[2 * ABUF + 4 * 4224];

  int bid = blockIdx.x;
  int g = bid % 72;      // (b,e1,e2): fixed XCD per group (72 % 8 == 0)
  int chunk = bid / 72;  // e3 chunk: 10 chunks of 6 rows + 1 of 2
  int b = g / 36;
  int e1 = (g / 6) % 6;
  int e2 = g % 6;
  int r0 = chunk * 6;

  if (chunk < 10)
    conv_body<3>(wTb, xbb, out, lds, b, e1, e2, r0);
  else
    conv_body<1>(wTb, xbb, out, lds, b, e1, e2, r0);
}

extern "C" void kernel_launch(void* const* d_in, const int* in_sizes, int n_in,
                              void* d_out, int out_size, void* d_ws,
                              size_t ws_size, hipStream_t stream) {
  const float* x = (const float*)d_in[0];
  const float* w = (const float*)d_in[1];
  float* out = (float*)d_out;
  unsigned char* ws = (unsigned char*)d_ws;
  prep<<<dim3(544), dim3(256), 0, stream>>>(x, w, ws);
  conv_mfma<<<dim3(792), dim3(256), 0, stream>>>(ws, out);
}